// Round 1
// baseline (915.507 us; speedup 1.0000x reference)
//
#include <hip/hip_runtime.h>
#include <math.h>

// Problem constants (fixed by reference): B=2, S=2048, D=2048, H=16, kd=128
#define M_    4096   // B*S
#define D_    2048
#define NQKV  2304   // D + 2*kd
#define NFUSE 4352   // D + NQKV  (fused GEMM N)
#define KD_   128
#define S_    2048

using bf16x8  = __attribute__((ext_vector_type(8))) __bf16;
using f32x4   = __attribute__((ext_vector_type(4))) float;
using ushort8 = __attribute__((ext_vector_type(8))) unsigned short;

// fp32 -> bf16 bits, round-to-nearest-even (values are normal; no NaN/Inf in inputs)
__device__ __forceinline__ unsigned short f2bf(float f) {
  unsigned int u = __builtin_bit_cast(unsigned int, f);
  u += 0x7fffu + ((u >> 16) & 1u);
  return (unsigned short)(u >> 16);
}

// async global->LDS, 16B per lane; LDS dst must be wave-uniform base + lane*16
#define GLL16(g, l) \
  __builtin_amdgcn_global_load_lds((__attribute__((address_space(1))) void*)(g), \
                                   (__attribute__((address_space(3))) void*)(l), 16, 0, 0)

// ---------------------------------------------------------------------------
// Prep 1: cast in_x fp32 -> bf16 (row-major [4096][2048])
__global__ void cast_x_kernel(const float* __restrict__ x, unsigned short* __restrict__ xb) {
  int i = (blockIdx.x * 256 + threadIdx.x) * 8;   // 8,388,608 elems = 4096*256*8 exactly
  float4 a = *(const float4*)(x + i);
  float4 b = *(const float4*)(x + i + 4);
  ushort8 o;
  o[0]=f2bf(a.x); o[1]=f2bf(a.y); o[2]=f2bf(a.z); o[3]=f2bf(a.w);
  o[4]=f2bf(b.x); o[5]=f2bf(b.y); o[6]=f2bf(b.z); o[7]=f2bf(b.w);
  *(ushort8*)(xb + i) = o;
}

// ---------------------------------------------------------------------------
// Prep 2: fused weight transpose+cast:  Wt[n][k] = (n<2048 ? W_sc[k][n] : W_qkv[k][n-2048])
// grid (64 k-tiles, 136 n-tiles), block (32,8)
__global__ void prep_w_kernel(const float* __restrict__ Wsc, const float* __restrict__ Wqkv,
                              unsigned short* __restrict__ Wt) {
  __shared__ float t[32][33];
  int k0 = blockIdx.x * 32, n0 = blockIdx.y * 32;
  int tx = threadIdx.x, ty = threadIdx.y;
  #pragma unroll
  for (int i = 0; i < 32; i += 8) {
    int k = k0 + ty + i, n = n0 + tx;
    t[ty + i][tx] = (n < D_) ? Wsc[(size_t)k * D_ + n] : Wqkv[(size_t)k * NQKV + (n - D_)];
  }
  __syncthreads();
  #pragma unroll
  for (int i = 0; i < 32; i += 8) {
    int n = n0 + ty + i, k = k0 + tx;
    Wt[(size_t)n * D_ + k] = f2bf(t[tx][ty + i]);
  }
}

// ---------------------------------------------------------------------------
// Fused GEMM: C = Xb(4096x2048) * W(2048x4352) + bias
//   n < 2048   -> short_cut (fp32 out)
//   n >= 2048  -> qkv (bf16 ws)
// m97 structure: 128x128 tile, BK=32, 4 waves (2x2 of 64x64), global_load_lds w16
__global__ __launch_bounds__(256, 2) void gemm_fused_kernel(
    const unsigned short* __restrict__ X,   // [4096][2048] bf16
    const unsigned short* __restrict__ Wt,  // [4352][2048] bf16 (pre-transposed)
    const float* __restrict__ b_sc, const float* __restrict__ b_qkv,
    float* __restrict__ shortcut, unsigned short* __restrict__ qkv) {
  __shared__ alignas(16) unsigned short As[128 * 32];
  __shared__ alignas(16) unsigned short Bs[128 * 32];
  const int tid = threadIdx.x;
  const int lane = tid & 63, wid = tid >> 6;
  const int l16 = lane & 15, quad = lane >> 4;
  const int wm = (wid >> 1) * 64, wn = (wid & 1) * 64;
  const int m0 = blockIdx.y * 128, n0 = blockIdx.x * 128;

  const int fa = tid * 16;  // flat byte offset this thread stages (issue 0)
  const char* aSrc0 = (const char*)X  + (size_t)(m0 + (fa >> 6)) * 4096 + (fa & 63);
  const char* aSrc1 = aSrc0 + (size_t)64 * 4096;
  const char* bSrc0 = (const char*)Wt + (size_t)(n0 + (fa >> 6)) * 4096 + (fa & 63);
  const char* bSrc1 = bSrc0 + (size_t)64 * 4096;
  char* aDst0 = (char*)As + fa; char* aDst1 = aDst0 + 4096;
  char* bDst0 = (char*)Bs + fa; char* bDst1 = bDst0 + 4096;

  f32x4 acc[4][4] = {};
  for (int kt = 0; kt < 64; ++kt) {
    __syncthreads();                       // prior compute done reading LDS
    GLL16(aSrc0, aDst0); GLL16(aSrc1, aDst1);
    GLL16(bSrc0, bDst0); GLL16(bSrc1, bDst1);
    aSrc0 += 64; aSrc1 += 64; bSrc0 += 64; bSrc1 += 64;
    __syncthreads();                       // vmcnt drained + barrier: tiles ready
    bf16x8 af[4], bfr[4];
    #pragma unroll
    for (int mi = 0; mi < 4; ++mi)
      af[mi] = *(const bf16x8*)(As + (wm + mi * 16 + l16) * 32 + quad * 8);
    #pragma unroll
    for (int ni = 0; ni < 4; ++ni)
      bfr[ni] = *(const bf16x8*)(Bs + (wn + ni * 16 + l16) * 32 + quad * 8);
    #pragma unroll
    for (int mi = 0; mi < 4; ++mi)
      #pragma unroll
      for (int ni = 0; ni < 4; ++ni)
        acc[mi][ni] = __builtin_amdgcn_mfma_f32_16x16x32_bf16(af[mi], bfr[ni], acc[mi][ni], 0, 0, 0);
  }

  // epilogue: C/D layout col=lane&15 (n), row=quad*4+reg (m)
  #pragma unroll
  for (int ni = 0; ni < 4; ++ni) {
    int n = n0 + wn + ni * 16 + l16;
    float bias = (n < D_) ? b_sc[n] : b_qkv[n - D_];
    #pragma unroll
    for (int mi = 0; mi < 4; ++mi) {
      #pragma unroll
      for (int r = 0; r < 4; ++r) {
        int m = m0 + wm + mi * 16 + quad * 4 + r;
        float v = acc[mi][ni][r] + bias;
        if (n < D_) shortcut[(size_t)m * D_ + n] = v;
        else        qkv[(size_t)m * NQKV + (n - D_)] = f2bf(v);
      }
    }
  }
}

// ---------------------------------------------------------------------------
// Prep 3: Vt[b][d][t] = qkv[b*2048+t][2176+d]   (bf16 transpose, per batch)
// grid (64 t-tiles, 4 d-tiles, 2 b), block (32,8)
__global__ void prep_vt_kernel(const unsigned short* __restrict__ qkv,
                               unsigned short* __restrict__ vt) {
  __shared__ unsigned short t[32][33];
  int b = blockIdx.z;
  int t0 = blockIdx.x * 32, d0 = blockIdx.y * 32;
  int tx = threadIdx.x, ty = threadIdx.y;
  #pragma unroll
  for (int i = 0; i < 32; i += 8)
    t[ty + i][tx] = qkv[(size_t)(b * S_ + t0 + ty + i) * NQKV + (D_ + KD_) + d0 + tx];
  __syncthreads();
  #pragma unroll
  for (int i = 0; i < 32; i += 8)
    vt[(size_t)(b * KD_ + d0 + ty + i) * S_ + t0 + tx] = t[tx][ty + i];
}

// ---------------------------------------------------------------------------
// Attention: per (b,h), Q-tile of 64 rows (1 wave = 16 rows), online softmax
// over 32 t-tiles of 64. Writes score tiles inline; atten/res at end.
__global__ __launch_bounds__(256, 2) void attn_kernel(
    const unsigned short* __restrict__ qkv,  // [4096][2304] bf16
    const unsigned short* __restrict__ vt,   // [2][128][2048] bf16 (V^T)
    float* __restrict__ score, float* __restrict__ atten, float* __restrict__ res) {
  // LDS layouts are k-panelized [kk][rows][32] so frag reads are ds_read_b128
  __shared__ alignas(16) unsigned short Qs[4 * 64 * 32];   // 16 KB
  __shared__ alignas(16) unsigned short Ks[4 * 64 * 32];   // 16 KB
  __shared__ alignas(16) unsigned short Vs[2 * 128 * 32];  // 16 KB
  __shared__ alignas(16) unsigned short Ps[2 * 64 * 32];   //  8 KB

  const int tid = threadIdx.x;
  const int lane = tid & 63, wid = tid >> 6;
  const int l16 = lane & 15, quad = lane >> 4;
  const int qt = blockIdx.x, bh = blockIdx.y;
  const int b = bh >> 4, h = bh & 15;
  const int q0 = qt * 64;

  // stage Q tile once (64 rows x 128 cols)
  {
    const char* qb = (const char*)qkv + (size_t)(b * S_ + q0) * (NQKV * 2) + h * (KD_ * 2);
    #pragma unroll
    for (int i = 0; i < 4; ++i) {
      int f = tid * 16 + i * 4096;
      GLL16(qb + (size_t)((f & 4095) >> 6) * (NQKV * 2) + (f >> 12) * 64 + (f & 63),
            (char*)Qs + f);
    }
  }
  __syncthreads();
  bf16x8 qf[4];
  #pragma unroll
  for (int kk = 0; kk < 4; ++kk)
    qf[kk] = *(const bf16x8*)(Qs + kk * 2048 + (wid * 16 + l16) * 32 + quad * 8);

  f32x4 acc_o[8] = {};
  float m_r[4] = {-1e30f, -1e30f, -1e30f, -1e30f};
  float l_r[4] = {0.f, 0.f, 0.f, 0.f};
  const float inv_scale = 1.0f / 16384.0f;  // 1/(kd*kd)

  const char* kb0 = (const char*)qkv + (size_t)b * S_ * (NQKV * 2) + D_ * 2;
  const char* vb0 = (const char*)vt + (size_t)b * KD_ * S_ * 2;

  for (int tt = 0; tt < 32; ++tt) {
    const int t0 = tt * 64;
    __syncthreads();                        // all waves done with previous K/V tiles
    #pragma unroll
    for (int i = 0; i < 4; ++i) {           // K tile: 64 t-rows x 128 d
      int f = tid * 16 + i * 4096;
      GLL16(kb0 + (size_t)(t0 + ((f & 4095) >> 6)) * (NQKV * 2) + (f >> 12) * 64 + (f & 63),
            (char*)Ks + f);
    }
    #pragma unroll
    for (int i = 0; i < 4; ++i) {           // V^T tile: 128 d-rows x 64 t
      int f = tid * 16 + i * 4096;
      GLL16(vb0 + (size_t)((f & 8191) >> 6) * (S_ * 2) + t0 * 2 + (f >> 13) * 64 + (f & 63),
            (char*)Vs + f);
    }
    __syncthreads();                        // tiles ready

    // S = Q K^T, scaled. Per wave: 16 q-rows x 64 t.
    f32x4 sa[4];
    #pragma unroll
    for (int jn = 0; jn < 4; ++jn) {
      f32x4 a = {};
      #pragma unroll
      for (int kk = 0; kk < 4; ++kk) {
        bf16x8 kf = *(const bf16x8*)(Ks + kk * 2048 + (jn * 16 + l16) * 32 + quad * 8);
        a = __builtin_amdgcn_mfma_f32_16x16x32_bf16(qf[kk], kf, a, 0, 0, 0);
      }
      #pragma unroll
      for (int r = 0; r < 4; ++r) a[r] *= inv_scale;
      sa[jn] = a;
    }

    // score write (pre-softmax), C layout: q = quad*4+r, t = jn*16+l16
    {
      float* sc = score + ((size_t)bh * S_ + q0 + wid * 16) * S_ + t0;
      #pragma unroll
      for (int jn = 0; jn < 4; ++jn)
        #pragma unroll
        for (int r = 0; r < 4; ++r)
          sc[(size_t)(quad * 4 + r) * S_ + jn * 16 + l16] = sa[jn][r];
    }

    // online softmax: row stats live replicated in the 16 lanes of each quad
    float mx[4];
    #pragma unroll
    for (int r = 0; r < 4; ++r)
      mx[r] = fmaxf(fmaxf(sa[0][r], sa[1][r]), fmaxf(sa[2][r], sa[3][r]));
    #pragma unroll
    for (int off = 8; off >= 1; off >>= 1)
      #pragma unroll
      for (int r = 0; r < 4; ++r) mx[r] = fmaxf(mx[r], __shfl_xor(mx[r], off, 16));
    float alpha[4];
    #pragma unroll
    for (int r = 0; r < 4; ++r) {
      float mn = fmaxf(m_r[r], mx[r]);
      alpha[r] = __expf(m_r[r] - mn);
      m_r[r] = mn;
    }
    float sm[4] = {0.f, 0.f, 0.f, 0.f};
    #pragma unroll
    for (int jn = 0; jn < 4; ++jn)
      #pragma unroll
      for (int r = 0; r < 4; ++r) {
        float p = __expf(sa[jn][r] - m_r[r]);
        sa[jn][r] = p;
        sm[r] += p;
      }
    #pragma unroll
    for (int off = 8; off >= 1; off >>= 1)
      #pragma unroll
      for (int r = 0; r < 4; ++r) sm[r] += __shfl_xor(sm[r], off, 16);
    #pragma unroll
    for (int r = 0; r < 4; ++r) l_r[r] = l_r[r] * alpha[r] + sm[r];
    #pragma unroll
    for (int dn = 0; dn < 8; ++dn)
      #pragma unroll
      for (int r = 0; r < 4; ++r) acc_o[dn][r] *= alpha[r];

    // P (C layout) -> LDS (A layout), per-wave rows only
    #pragma unroll
    for (int jn = 0; jn < 4; ++jn) {
      int t = jn * 16 + l16;
      #pragma unroll
      for (int r = 0; r < 4; ++r)
        Ps[(t >> 5) * 2048 + (wid * 16 + quad * 4 + r) * 32 + (t & 31)] = f2bf(sa[jn][r]);
    }
    __syncthreads();   // conservative: orders P write -> P read (cross-lane in wave)

    // O += P V  (A = P[q][t], B-frag from V^T[d][t])
    #pragma unroll
    for (int kkt = 0; kkt < 2; ++kkt) {
      bf16x8 pf = *(const bf16x8*)(Ps + kkt * 2048 + (wid * 16 + l16) * 32 + quad * 8);
      #pragma unroll
      for (int dn = 0; dn < 8; ++dn) {
        bf16x8 vf = *(const bf16x8*)(Vs + kkt * 4096 + (dn * 16 + l16) * 32 + quad * 8);
        acc_o[dn] = __builtin_amdgcn_mfma_f32_16x16x32_bf16(pf, vf, acc_o[dn], 0, 0, 0);
      }
    }
  }

  // epilogue: atten[b][h][q][d] and res[b][q][h*128+d]
  #pragma unroll
  for (int dn = 0; dn < 8; ++dn) {
    int d = dn * 16 + l16;
    #pragma unroll
    for (int r = 0; r < 4; ++r) {
      int q = q0 + wid * 16 + quad * 4 + r;
      float v = acc_o[dn][r] / l_r[r];
      atten[((size_t)bh * S_ + q) * KD_ + d] = v;
      res[((size_t)b * S_ + q) * D_ + h * KD_ + d] = v;
    }
  }
}

// ---------------------------------------------------------------------------
extern "C" void kernel_launch(void* const* d_in, const int* in_sizes, int n_in,
                              void* d_out, int out_size, void* d_ws, size_t ws_size,
                              hipStream_t stream) {
  (void)in_sizes; (void)n_in; (void)out_size; (void)ws_size;
  const float* in_x  = (const float*)d_in[0];
  const float* W_sc  = (const float*)d_in[1];
  const float* b_sc  = (const float*)d_in[2];
  const float* W_qkv = (const float*)d_in[3];
  const float* b_qkv = (const float*)d_in[4];

  char* ws = (char*)d_ws;
  unsigned short* Xb  = (unsigned short*)ws;                          // 16,777,216 B
  unsigned short* Wt  = (unsigned short*)(ws + 16777216);             // 17,825,792 B
  unsigned short* qkv = (unsigned short*)(ws + 16777216 + 17825792);  // 18,874,368 B
  unsigned short* Vt  = (unsigned short*)(ws + 16777216 + 17825792 + 18874368);  // 1,048,576 B

  float* score    = (float*)d_out;            // 2*16*2048*2048 = 134217728
  float* atten    = score + 134217728;        // 8388608
  float* res      = atten + 8388608;          // 8388608
  float* shortcut = res + 8388608;            // 8388608

  cast_x_kernel<<<4096, 256, 0, stream>>>(in_x, Xb);
  prep_w_kernel<<<dim3(64, 136), dim3(32, 8), 0, stream>>>(W_sc, W_qkv, Wt);
  gemm_fused_kernel<<<dim3(34, 32), 256, 0, stream>>>(Xb, Wt, b_sc, b_qkv, shortcut, qkv);
  prep_vt_kernel<<<dim3(64, 4, 2), dim3(32, 8), 0, stream>>>(qkv, Vt);
  attn_kernel<<<dim3(32, 32), 256, 0, stream>>>(qkv, Vt, score, atten, res);
}